// Round 1
// baseline (28.512 us; speedup 1.0000x reference)
//
#include <hip/hip_runtime.h>

#define NB 16
#define NT 512
#define ND 384
#define NMEL 4096

// ---------------- Kernel A: scan + frame-index precompute -----------------
__global__ __launch_bounds__(NT) void dr_scan_kernel(
    const int* __restrict__ tl32,         // token_lengths (int32 or int64 layout)
    const int* __restrict__ token_durations, // [NB][NT] int32
    const int* __restrict__ alpha_ptr,    // scalar
    int* __restrict__ idx_enc,            // [NB][NMEL] out: idx or -1
    float* __restrict__ mel_lens)         // [NB] out
{
    __shared__ int s[NT];
    const int b = blockIdx.x;
    const int t = threadIdx.x;

    // ---- detect token_lengths element width ----
    // lengths are in [1, NT]; if stored as int64 (little-endian), the odd
    // int32 slots of the first 16 int32s are all zero (high words).
    bool is64 = true;
    #pragma unroll
    for (int i = 1; i < NB; i += 2) {
        if (tl32[i] != 0) { is64 = false; }
    }
    const int len = is64 ? tl32[2 * b] : tl32[b];

    // ---- alpha decode (benchmark uses 1; accept int-bits or float-bits) ----
    const int araw = alpha_ptr[0];
    const float abits = __int_as_float(araw);
    const bool alpha_one = (araw == 1) || (abits == 1.0f);

    int dur = token_durations[b * NT + t];
    if (!alpha_one) {
        float a = (abits > 0.001f && abits < 1000.0f) ? abits : (float)araw;
        dur = (int)rintf((float)dur * a);   // rint = round-half-even, matches jnp.round
    }
    if (t >= len) dur = 0;
    s[t] = dur;
    __syncthreads();

    // Hillis-Steele inclusive scan over NT=512
    for (int off = 1; off < NT; off <<= 1) {
        int v = (t >= off) ? s[t - off] : 0;
        __syncthreads();
        s[t] += v;
        __syncthreads();
    }
    const int total = s[NT - 1];
    if (t == NT - 1) mel_lens[b] = (float)total;

    // each thread resolves NMEL/NT = 8 frames via binary search in LDS
    #pragma unroll
    for (int k = 0; k < NMEL / NT; ++k) {
        const int f = t + k * NT;
        // searchsorted(side='right'): first index with s[idx] > f
        int lo = 0, hi = NT;
        while (lo < hi) {
            const int mid = (lo + hi) >> 1;
            if (s[mid] <= f) lo = mid + 1; else hi = mid;
        }
        int idx = (lo < NT) ? lo : (NT - 1);   // clip to T-1
        idx_enc[b * NMEL + f] = (f < total) ? idx : -1;
    }
}

// ---------------- Kernel B: row gather, float4-vectorized -----------------
__global__ __launch_bounds__(256) void dr_gather_kernel(
    const float4* __restrict__ batch,   // [NB*NT*ND/4]
    const int* __restrict__ idx_enc,    // [NB*NMEL]
    float4* __restrict__ out)           // [NB*NMEL*ND/4]
{
    const int ROWV = ND / 4;                       // 96 float4 per row
    const int total = NB * NMEL * ROWV;            // 6,291,456
    const int stride = gridDim.x * blockDim.x;
    for (int e = blockIdx.x * blockDim.x + threadIdx.x; e < total; e += stride) {
        const int row = e / ROWV;                  // (b, frame)
        const int col = e - row * ROWV;
        const int enc = idx_enc[row];
        float4 v;
        if (enc >= 0) {
            const int b = row >> 12;               // row / NMEL
            v = batch[((size_t)b * NT + enc) * ROWV + col];
        } else {
            v = make_float4(0.f, 0.f, 0.f, 0.f);
        }
        out[e] = v;
    }
}

extern "C" void kernel_launch(void* const* d_in, const int* in_sizes, int n_in,
                              void* d_out, int out_size, void* d_ws, size_t ws_size,
                              hipStream_t stream) {
    const float* batch = (const float*)d_in[0];
    const int*   tl    = (const int*)d_in[1];
    const int*   td    = (const int*)d_in[2];
    const int*   alpha = (const int*)d_in[3];

    float* out      = (float*)d_out;
    float* mel_lens = out + (size_t)NB * NMEL * ND;   // second tuple output
    int*   idx_enc  = (int*)d_ws;                     // NB*NMEL*4 = 256 KB

    dr_scan_kernel<<<NB, NT, 0, stream>>>(tl, td, alpha, idx_enc, mel_lens);
    dr_gather_kernel<<<4096, 256, 0, stream>>>(
        (const float4*)batch, idx_enc, (float4*)out);
}

// Round 2
// 24.422 us; speedup vs baseline: 1.1675x; 1.1675x over previous
//
#include <hip/hip_runtime.h>

#define NB   16
#define NT   512
#define ND   384
#define NMEL 4096
#define ROWV (ND / 4)      // 96 float4 per row
#define BPB  128           // blocks per batch
#define FPB  (NMEL / BPB)  // 32 frames per block
#define NTHR 256

// One fused kernel: each block = (batch b, frame-chunk). Block recomputes the
// masked-duration inclusive scan for its batch in LDS (cheap, L2-hot), binary
// searches its 32 frames, then streams the gathered rows with float4 stores.
__global__ __launch_bounds__(NTHR) void dr_fused_kernel(
    const float4* __restrict__ batch,  // [NB*NT*ROWV]
    const int*    __restrict__ tl32,   // token_lengths (int32 or int64 layout)
    const int*    __restrict__ td,     // [NB][NT] int32 durations
    const int*    __restrict__ alpha_ptr,
    float4*       __restrict__ out,    // [NB*NMEL*ROWV]
    float*        __restrict__ mel_lens) // [NB]
{
    const int b     = blockIdx.x >> 7;        // / BPB
    const int chunk = blockIdx.x & (BPB - 1);
    const int t     = threadIdx.x;

    __shared__ int sA[NT];
    __shared__ int sB[NT];
    __shared__ int s_idx[FPB];

    // ---- token_lengths element-width detection ----
    // lengths in [1, NT]: if int64 (LE), odd int32 slots of first NB words are
    // all-zero high words; if int32, they are lengths >= 1 (nonzero).
    bool is64 = true;
    #pragma unroll
    for (int i = 1; i < NB; i += 2) {
        if (tl32[i] != 0) is64 = false;
    }
    const int len = is64 ? tl32[2 * b] : tl32[b];

    // ---- alpha decode (bench uses 1; accept int-bits or float-bits) ----
    const int   araw  = alpha_ptr[0];
    const float abits = __int_as_float(araw);
    const bool  alpha_one = (araw == 1) || (abits == 1.0f);

    // ---- load + mask durations ----
    #pragma unroll
    for (int i = t; i < NT; i += NTHR) {
        int d = td[b * NT + i];
        if (!alpha_one) {
            float a = (abits > 0.001f && abits < 1000.0f) ? abits : (float)araw;
            d = (int)rintf((float)d * a);  // round-half-even, matches jnp.round
        }
        if (i >= len) d = 0;
        sA[i] = d;
    }
    __syncthreads();

    // ---- Hillis-Steele inclusive scan of 512 elems, 256 threads, ping-pong ----
    int* src = sA;
    int* dst = sB;
    for (int off = 1; off < NT; off <<= 1) {
        #pragma unroll
        for (int i = t; i < NT; i += NTHR) {
            dst[i] = src[i] + ((i >= off) ? src[i - off] : 0);
        }
        __syncthreads();
        int* tmp = src; src = dst; dst = tmp;
    }
    const int total = src[NT - 1];
    if (chunk == 0 && t == 0) mel_lens[b] = (float)total;

    // ---- resolve this chunk's 32 frame indices ----
    const int f0 = chunk * FPB;
    if (t < FPB) {
        const int f = f0 + t;
        // searchsorted(side='right'): first index with csum[idx] > f
        int lo = 0, hi = NT;
        while (lo < hi) {
            const int mid = (lo + hi) >> 1;
            if (src[mid] <= f) lo = mid + 1; else hi = mid;
        }
        int idx = (lo < NT) ? lo : (NT - 1);  // clip to T-1
        s_idx[t] = (f < total) ? idx : -1;
    }
    __syncthreads();

    // ---- gather + stream: FPB*ROWV = 3072 float4 per block, 12 per thread ----
    const float4* brow = batch + (size_t)b * NT * ROWV;
    float4*       orow = out + ((size_t)b * NMEL + f0) * ROWV;
    #pragma unroll
    for (int i = 0; i < (FPB * ROWV) / NTHR; ++i) {
        const int e   = t + i * NTHR;
        const int fl  = e / ROWV;          // frame within chunk
        const int col = e - fl * ROWV;
        const int enc = s_idx[fl];
        float4 v;
        if (enc >= 0) {
            v = brow[(size_t)enc * ROWV + col];
        } else {
            v = make_float4(0.f, 0.f, 0.f, 0.f);
        }
        orow[e] = v;
    }
}

extern "C" void kernel_launch(void* const* d_in, const int* in_sizes, int n_in,
                              void* d_out, int out_size, void* d_ws, size_t ws_size,
                              hipStream_t stream) {
    const float* batch = (const float*)d_in[0];
    const int*   tl    = (const int*)d_in[1];
    const int*   td    = (const int*)d_in[2];
    const int*   alpha = (const int*)d_in[3];

    float* out      = (float*)d_out;
    float* mel_lens = out + (size_t)NB * NMEL * ND;  // second tuple output

    dr_fused_kernel<<<NB * BPB, NTHR, 0, stream>>>(
        (const float4*)batch, tl, td, alpha, (float4*)out, mel_lens);
}